// Round 1
// baseline (19771.280 us; speedup 1.0000x reference)
//
#include <hip/hip_runtime.h>
#include <hip/hip_bf16.h>
#include <math.h>

#define BATCH 64
#define TLEN  512
#define DIN   300
#define RDIM  2048

typedef __attribute__((ext_vector_type(4))) float f32x4;
typedef __attribute__((ext_vector_type(8))) short bf16x8;

__device__ __forceinline__ unsigned short f32_bf16_rne(float f) {
    unsigned int u = __float_as_uint(f);
    u += 0x7fffu + ((u >> 16) & 1u);
    return (unsigned short)(u >> 16);
}
__device__ __forceinline__ float bf16_f32(unsigned short h) {
    return __uint_as_float(((unsigned int)h) << 16);
}

// ---------------- W -> bf16 hi/lo split (one-time) ----------------
__global__ __launch_bounds__(256) void k_wsplit(const float* __restrict__ W,
                                                unsigned short* __restrict__ Whi,
                                                unsigned short* __restrict__ Wlo) {
    int i = (blockIdx.x * 256 + threadIdx.x) * 4;
    f32x4 w = *(const f32x4*)(W + i);
    ushort4 hi, lo;
    unsigned short h0 = f32_bf16_rne(w[0]); hi.x = h0; lo.x = f32_bf16_rne(w[0] - bf16_f32(h0));
    unsigned short h1 = f32_bf16_rne(w[1]); hi.y = h1; lo.y = f32_bf16_rne(w[1] - bf16_f32(h1));
    unsigned short h2 = f32_bf16_rne(w[2]); hi.z = h2; lo.z = f32_bf16_rne(w[2] - bf16_f32(h2));
    unsigned short h3 = f32_bf16_rne(w[3]); hi.w = h3; lo.w = f32_bf16_rne(w[3] - bf16_f32(h3));
    *(ushort4*)(Whi + i) = hi;
    *(ushort4*)(Wlo + i) = lo;
}

// ---------------- Kernel A: U = x @ Win^T (fp32), writes into out ----------------
// M = B*T = 32768 (m = b*512 + t), N = R = 2048, K = D = 300.
// For t==0 writes h0 = tanh(U0) (and its bf16 split if enabled).
#define A_BM 128
#define A_BN 64
#define A_BK 20
#define XS_STRIDE 132   // 128 + 4 pad (bank spread, keeps 16B align)
#define WS_STRIDE 68    // 64 + 4 pad

__global__ __launch_bounds__(256) void k_proj(const float* __restrict__ x,
                                              const float* __restrict__ Win,
                                              float* __restrict__ hseq,
                                              unsigned short* h0hi,
                                              unsigned short* h0lo,
                                              int do_split) {
    __shared__ __align__(16) float xs[A_BK * XS_STRIDE];
    __shared__ __align__(16) float wsh[A_BK * WS_STRIDE];
    const int tid = threadIdx.x;
    const int tx = tid & 15;        // n direction (4 cols each)
    const int ty = tid >> 4;        // m direction (8 rows each)
    const int m0 = blockIdx.y * A_BM;
    const int n0 = blockIdx.x * A_BN;

    float acc[8][4];
#pragma unroll
    for (int i = 0; i < 8; ++i)
#pragma unroll
        for (int j = 0; j < 4; ++j) acc[i][j] = 0.0f;

    for (int k0 = 0; k0 < DIN; k0 += A_BK) {
        // stage x tile [128 m x 20 k] transposed -> xs[k][m]
#pragma unroll
        for (int s = 0; s < (A_BM * A_BK) / 256; ++s) {
            int idx = tid + s * 256;
            int row = idx / A_BK, col = idx - row * A_BK;
            xs[col * XS_STRIDE + row] = x[(m0 + row) * DIN + k0 + col];
        }
        // stage Win tile [64 n x 20 k] transposed -> wsh[k][n]
#pragma unroll
        for (int s = 0; s < (A_BN * A_BK) / 256; ++s) {
            int idx = tid + s * 256;
            int row = idx / A_BK, col = idx - row * A_BK;
            wsh[col * WS_STRIDE + row] = Win[(n0 + row) * DIN + k0 + col];
        }
        __syncthreads();
#pragma unroll
        for (int kk = 0; kk < A_BK; ++kk) {
            f32x4 xv0 = *(const f32x4*)&xs[kk * XS_STRIDE + ty * 8];
            f32x4 xv1 = *(const f32x4*)&xs[kk * XS_STRIDE + ty * 8 + 4];
            f32x4 wv  = *(const f32x4*)&wsh[kk * WS_STRIDE + tx * 4];
#pragma unroll
            for (int i = 0; i < 4; ++i)
#pragma unroll
                for (int j = 0; j < 4; ++j) acc[i][j] += xv0[i] * wv[j];
#pragma unroll
            for (int i = 0; i < 4; ++i)
#pragma unroll
                for (int j = 0; j < 4; ++j) acc[4 + i][j] += xv1[i] * wv[j];
        }
        __syncthreads();
    }

    // epilogue
#pragma unroll
    for (int i = 0; i < 8; ++i) {
        int m = m0 + ty * 8 + i;
        int t = m & (TLEN - 1);
        int b = m >> 9;
        int r0 = n0 + tx * 4;
        f32x4 v;
#pragma unroll
        for (int j = 0; j < 4; ++j) v[j] = acc[i][j];
        if (t == 0) {
#pragma unroll
            for (int j = 0; j < 4; ++j) v[j] = tanhf(v[j]);
            if (do_split) {
#pragma unroll
                for (int j = 0; j < 4; ++j) {
                    unsigned short hi = f32_bf16_rne(v[j]);
                    h0hi[b * RDIM + r0 + j] = hi;
                    h0lo[b * RDIM + r0 + j] = f32_bf16_rne(v[j] - bf16_f32(hi));
                }
            }
        }
        *(f32x4*)(hseq + ((size_t)t * BATCH + b) * RDIM + r0) = v;
    }
}

// ---------------- Step kernel: h_t = blend(tanh(U_t + h_{t-1} @ W^T)) ----------------
// Grid: 128 blocks (n-slices of 16), 256 threads = 4 waves (m-subtiles of 16).
// mfma_f32_16x16x32_bf16; split-precision: hhi*Whi + hlo*Whi + hhi*Wlo.
template <bool SPLIT>
__global__ __launch_bounds__(256) void k_step(float* hseq,  // [T][B][R], not restrict (read U_t / write h_t)
                                              const unsigned short* __restrict__ Whi,
                                              const unsigned short* __restrict__ Wlo,
                                              const float* __restrict__ Wf,
                                              const unsigned short* __restrict__ hphi,
                                              const unsigned short* __restrict__ hplo,
                                              unsigned short* __restrict__ hchi,
                                              unsigned short* __restrict__ hclo,
                                              int t) {
    const int lane = threadIdx.x & 63;
    const int wave = threadIdx.x >> 6;
    const int l15 = lane & 15;
    const int q = lane >> 4;
    const int n0 = blockIdx.x * 16;
    const int m0 = wave * 16;

    const int arow = m0 + l15;   // batch row for A fragment
    const int brow = n0 + l15;   // W row (output col) for B fragment
    const int kbase = q * 8;

    f32x4 acc = {0.f, 0.f, 0.f, 0.f};
    const float* hprev_f = hseq + (size_t)(t - 1) * BATCH * RDIM;

    if (SPLIT) {
        const unsigned short* ah = hphi + arow * RDIM + kbase;
        const unsigned short* al = hplo + arow * RDIM + kbase;
        const unsigned short* bh = Whi + brow * RDIM + kbase;
        const unsigned short* bl = Wlo + brow * RDIM + kbase;
#pragma unroll 4
        for (int k = 0; k < RDIM; k += 32) {
            bf16x8 ahi = *(const bf16x8*)(ah + k);
            bf16x8 alo = *(const bf16x8*)(al + k);
            bf16x8 bhi = *(const bf16x8*)(bh + k);
            bf16x8 blo = *(const bf16x8*)(bl + k);
            acc = __builtin_amdgcn_mfma_f32_16x16x32_bf16(ahi, bhi, acc, 0, 0, 0);
            acc = __builtin_amdgcn_mfma_f32_16x16x32_bf16(alo, bhi, acc, 0, 0, 0);
            acc = __builtin_amdgcn_mfma_f32_16x16x32_bf16(ahi, blo, acc, 0, 0, 0);
        }
    } else {
        const float* af = hprev_f + arow * RDIM + kbase;
        const float* bfp = Wf + brow * RDIM + kbase;
#pragma unroll 2
        for (int k = 0; k < RDIM; k += 32) {
            f32x4 a0 = *(const f32x4*)(af + k);
            f32x4 a1 = *(const f32x4*)(af + k + 4);
            f32x4 b0 = *(const f32x4*)(bfp + k);
            f32x4 b1 = *(const f32x4*)(bfp + k + 4);
            bf16x8 ahi, alo, bhi, blo;
#pragma unroll
            for (int j = 0; j < 4; ++j) {
                unsigned short h;
                h = f32_bf16_rne(a0[j]); ahi[j] = (short)h; alo[j] = (short)f32_bf16_rne(a0[j] - bf16_f32(h));
                h = f32_bf16_rne(a1[j]); ahi[4 + j] = (short)h; alo[4 + j] = (short)f32_bf16_rne(a1[j] - bf16_f32(h));
                h = f32_bf16_rne(b0[j]); bhi[j] = (short)h; blo[j] = (short)f32_bf16_rne(b0[j] - bf16_f32(h));
                h = f32_bf16_rne(b1[j]); bhi[4 + j] = (short)h; blo[4 + j] = (short)f32_bf16_rne(b1[j] - bf16_f32(h));
            }
            acc = __builtin_amdgcn_mfma_f32_16x16x32_bf16(ahi, bhi, acc, 0, 0, 0);
            acc = __builtin_amdgcn_mfma_f32_16x16x32_bf16(alo, bhi, acc, 0, 0, 0);
            acc = __builtin_amdgcn_mfma_f32_16x16x32_bf16(ahi, blo, acc, 0, 0, 0);
        }
    }

    // epilogue: C/D layout col = lane&15, row = (lane>>4)*4 + reg
    float* outt = hseq + (size_t)t * BATCH * RDIM;
#pragma unroll
    for (int v = 0; v < 4; ++v) {
        int b = m0 + q * 4 + v;
        size_t o = (size_t)b * RDIM + brow;
        float raw = tanhf(acc[v] + outt[o]);
        float hp = hprev_f[o];
        float h = (t >= 2) ? 0.5f * raw + 0.5f * hp : raw;
        outt[o] = h;
        if (SPLIT) {
            unsigned short hi = f32_bf16_rne(h);
            hchi[o] = hi;
            hclo[o] = f32_bf16_rne(h - bf16_f32(hi));
        }
    }
}

extern "C" void kernel_launch(void* const* d_in, const int* in_sizes, int n_in,
                              void* d_out, int out_size, void* d_ws, size_t ws_size,
                              hipStream_t stream) {
    const float* x   = (const float*)d_in[0];
    const float* Win = (const float*)d_in[1];
    const float* W   = (const float*)d_in[2];
    float* out = (float*)d_out;

    const size_t wElems = (size_t)RDIM * RDIM;
    const size_t hElems = (size_t)BATCH * RDIM;
    const size_t need = wElems * 2 * sizeof(unsigned short) + hElems * 4 * sizeof(unsigned short);
    const bool split = ws_size >= need;

    unsigned short* Whi = (unsigned short*)d_ws;
    unsigned short* Wlo = Whi + wElems;
    unsigned short* hb  = Wlo + wElems;
    unsigned short* hhi[2] = { hb,              hb + 2 * hElems };
    unsigned short* hlo[2] = { hb + hElems,     hb + 3 * hElems };

    if (split) {
        k_wsplit<<<(int)(wElems / 1024), 256, 0, stream>>>(W, Whi, Wlo);
    }

    dim3 gA(RDIM / A_BN, (BATCH * TLEN) / A_BM);
    k_proj<<<gA, 256, 0, stream>>>(x, Win, out, split ? hhi[0] : nullptr,
                                   split ? hlo[0] : nullptr, split ? 1 : 0);

    for (int t = 1; t < TLEN; ++t) {
        if (split) {
            k_step<true><<<RDIM / 16, 256, 0, stream>>>(out, Whi, Wlo, nullptr,
                                                        hhi[(t - 1) & 1], hlo[(t - 1) & 1],
                                                        hhi[t & 1], hlo[t & 1], t);
        } else {
            k_step<false><<<RDIM / 16, 256, 0, stream>>>(out, nullptr, nullptr, W,
                                                         nullptr, nullptr, nullptr, nullptr, t);
        }
    }
}